// Round 1
// baseline (155.378 us; speedup 1.0000x reference)
//
#include <hip/hip_runtime.h>
#include <hip/hip_bf16.h>

// Problem constants (fixed by the reference's setup_inputs).
constexpr int N_NODES  = 100000;
constexpr int BATCH    = 256;
constexpr int NUM_RELS = 200;
constexpr int VEC      = 300;
constexpr int DIM      = 32;
constexpr int MODES    = 6;

// ---- dtype-generic scalar load/store --------------------------------------
template <typename T> __device__ __forceinline__ float ldf(const void* p, int i);
template <> __device__ __forceinline__ float ldf<float>(const void* p, int i) {
    return ((const float*)p)[i];
}
template <> __device__ __forceinline__ float ldf<__hip_bfloat16>(const void* p, int i) {
    return __bfloat162float(((const __hip_bfloat16*)p)[i]);
}

// ---- dtype detector --------------------------------------------------------
// Reads the first 64 halfwords of rel_vectors interpreted as bf16.
// True bf16 N(0,1) data: all exponents <= ~129. fp32 data read as halfwords:
// the low-mantissa halfwords have ~uniform random exponent bits -> some value
// with exponent > 140 appears with probability ~1-1e-11.
__global__ void k_detect(const void* rel_vectors, int* flag) {
    if (blockIdx.x == 0 && threadIdx.x == 0) {
        const unsigned short* p = (const unsigned short*)rel_vectors;
        int isbf = 1;
        for (int i = 0; i < 64; ++i) {
            int expo = (p[i] >> 7) & 0xFF;
            if (expo > 140) isbf = 0;   // |v| > ~2^13: implausible for N(0,1)
        }
        *flag = isbf;
    }
}

// ---- workspace init (ws is re-poisoned to 0xAA before every launch) -------
__global__ void k_fill(int* ibase, int icount, float* fbase, int fcount) {
    const int stride = gridDim.x * blockDim.x;
    const int i = blockIdx.x * blockDim.x + threadIdx.x;
    for (int j = i; j < icount; j += stride) ibase[j] = -1;
    for (int j = i; j < fcount; j += stride) fbase[j] = 0.0f;
}

__global__ void k_scatter(const int* __restrict__ head_ids, const int* __restrict__ tail_ids,
                          int* hb, int* tb, int b) {
    const int t = blockIdx.x * blockDim.x + threadIdx.x;
    if (t < b) {
        hb[head_ids[t]] = t;
        tb[tail_ids[t]] = t;
    }
}

// ---- per-relation embedding + per-mode transforms --------------------------
// E_rel[r] = (rel_vectors[r] @ W1 + b1) @ W2 + b2            [200, 32]
// Y_rel[m][r] = E_rel[r] @ reld_W[m] + reld_b[m]             [6, 200, 32]
template <typename T>
__device__ __forceinline__ void rel_body(const void* rel_vectors, const void* W1, const void* b1,
                                         const void* W2, const void* b2,
                                         const void* reld_W, const void* reld_b,
                                         float* E_rel, float* Y_rel,
                                         float* rv, float* e1, float* e2) {
    const int r = blockIdx.x;
    const int d = threadIdx.x;
    for (int v = d; v < VEC; v += DIM) rv[v] = ldf<T>(rel_vectors, r * VEC + v);
    __syncthreads();
    float acc = ldf<T>(b1, d);
    for (int v = 0; v < VEC; ++v) acc += rv[v] * ldf<T>(W1, v * DIM + d);
    e1[d] = acc;
    __syncthreads();
    float acc2 = ldf<T>(b2, d);
    for (int k = 0; k < DIM; ++k) acc2 += e1[k] * ldf<T>(W2, k * DIM + d);
    e2[d] = acc2;
    E_rel[r * DIM + d] = acc2;
    __syncthreads();
    for (int m = 0; m < MODES; ++m) {
        float y = ldf<T>(reld_b, m * DIM + d);
        for (int k = 0; k < DIM; ++k) y += e2[k] * ldf<T>(reld_W, (m * DIM + k) * DIM + d);
        Y_rel[(m * NUM_RELS + r) * DIM + d] = y;
    }
}

__global__ void k_rel(const void* rel_vectors, const void* W1, const void* b1,
                      const void* W2, const void* b2,
                      const void* reld_W, const void* reld_b,
                      const int* flag, float* E_rel, float* Y_rel) {
    __shared__ float rv[VEC];
    __shared__ float e1[DIM];
    __shared__ float e2[DIM];
    if (*flag)
        rel_body<__hip_bfloat16>(rel_vectors, W1, b1, W2, b2, reld_W, reld_b, E_rel, Y_rel, rv, e1, e2);
    else
        rel_body<float>(rel_vectors, W1, b1, W2, b2, reld_W, reld_b, E_rel, Y_rel, rv, e1, e2);
}

// ---- edge scan: segment classification + sparse accumulation ---------------
__global__ void k_edges(const int* __restrict__ src, const int* __restrict__ dst,
                        const int* __restrict__ typ,
                        const int* __restrict__ hb, const int* __restrict__ tb,
                        const float* __restrict__ Y_rel,
                        float* agg, float* cntf, int n_edges) {
    const int stride = gridDim.x * blockDim.x;
    for (int e = blockIdx.x * blockDim.x + threadIdx.x; e < n_edges; e += stride) {
        const int s = src[e];
        const int dn = dst[e];
        const int hbs = hb[s], hbd = hb[dn], tbs = tb[s], tbd = tb[dn];
        if (hbs < 0 && hbd < 0 && tbs < 0 && tbd < 0) continue;  // ~99% of edges
        const int t = typ[e];  // lazy: only read for contributing edges
        const bool m5 = (hbs >= 0) && (hbs == tbd);
        const bool m6 = (hbd >= 0) && (hbd == tbs);
        int seg[MODES];
        seg[0] = (hbd >= 0 && !m6) ? hbd : -1;  // in_edge_out  - mode6
        seg[1] = (hbs >= 0 && !m5) ? hbs : -1;  // out_edge_out - mode5
        seg[2] = (tbd >= 0 && !m5) ? tbd : -1;  // in_edge_in   - mode5
        seg[3] = (tbs >= 0 && !m6) ? tbs : -1;  // out_edge_in  - mode6
        seg[4] = m5 ? hbs : -1;                 // mode5
        seg[5] = m6 ? hbd : -1;                 // mode6
        for (int m = 0; m < MODES; ++m) {
            const int b = seg[m];
            if (b < 0) continue;
            const float* y = Y_rel + (m * NUM_RELS + t) * DIM;
            float* a = agg + (m * BATCH + b) * DIM;
            #pragma unroll
            for (int d2 = 0; d2 < DIM; ++d2) atomicAdd(a + d2, y[d2]);
            atomicAdd(cntf + m * BATCH + b, 1.0f);
        }
    }
}

// ---- epilogue: mean-of-means, concat MLP, relu, L2-normalize, fc -----------
template <typename T>
__device__ __forceinline__ void final_body(const float* __restrict__ agg, const float* __restrict__ cntf,
                                           const float* __restrict__ E_rel, const int* __restrict__ rel_labels,
                                           const void* conc_W, const void* conc_b,
                                           const void* fc_W, const void* fc_b,
                                           void* out, float* cat) {
    const int b = blockIdx.x;
    const int d = threadIdx.x;
    float acc = 0.0f;
    for (int m = 0; m < MODES; ++m) {
        const float a = agg[(m * BATCH + b) * DIM + d];
        const float c = cntf[m * BATCH + b];
        acc += a / (c + 1e-30f);
    }
    cat[d] = acc / (float)MODES;          // rel_neighbor
    const int lab = rel_labels[b];
    cat[DIM + d] = E_rel[lab * DIM + d];  // r branch
    __syncthreads();
    float h = ldf<T>(conc_b, d);
    for (int k = 0; k < 2 * DIM; ++k) h += cat[k] * ldf<T>(conc_W, k * DIM + d);
    h = fmaxf(h, 0.0f);
    float n2 = h * h;
    #pragma unroll
    for (int off = 16; off >= 1; off >>= 1) n2 += __shfl_xor(n2, off);
    const float denom = fmaxf(sqrtf(n2), 1e-12f);
    const float g = h / denom;
    float prod = g * ldf<T>(fc_W, d);
    #pragma unroll
    for (int off = 16; off >= 1; off >>= 1) prod += __shfl_xor(prod, off);
    if (d == 0) {
        const float o = prod + ldf<T>(fc_b, 0);
        if constexpr (sizeof(T) == 2) ((__hip_bfloat16*)out)[b] = __float2bfloat16(o);
        else                          ((float*)out)[b] = o;
    }
}

__global__ void k_final(const float* __restrict__ agg, const float* __restrict__ cntf,
                        const float* __restrict__ E_rel, const int* __restrict__ rel_labels,
                        const void* conc_W, const void* conc_b,
                        const void* fc_W, const void* fc_b,
                        const int* flag, void* out) {
    __shared__ float cat[2 * DIM];
    if (*flag)
        final_body<__hip_bfloat16>(agg, cntf, E_rel, rel_labels, conc_W, conc_b, fc_W, fc_b, out, cat);
    else
        final_body<float>(agg, cntf, E_rel, rel_labels, conc_W, conc_b, fc_W, fc_b, out, cat);
}

extern "C" void kernel_launch(void* const* d_in, const int* in_sizes, int n_in,
                              void* d_out, int out_size, void* d_ws, size_t ws_size,
                              hipStream_t stream) {
    const int* edge_src   = (const int*)d_in[0];
    const int* edge_dst   = (const int*)d_in[1];
    const int* edge_type  = (const int*)d_in[2];
    const int* head_ids   = (const int*)d_in[3];
    const int* tail_ids   = (const int*)d_in[4];
    const int* rel_labels = (const int*)d_in[5];
    const void* rel_vectors = d_in[6];
    const void* W1     = d_in[7];
    const void* b1     = d_in[8];
    const void* W2     = d_in[9];
    const void* b2     = d_in[10];
    const void* reld_W = d_in[11];
    const void* reld_b = d_in[12];
    const void* conc_W = d_in[13];
    const void* conc_b = d_in[14];
    const void* fc_W   = d_in[15];
    const void* fc_b   = d_in[16];

    const int n_edges = in_sizes[0];

    // workspace layout (~2.2 MB)
    int*   hb    = (int*)d_ws;                       // N_NODES
    int*   tb    = hb + N_NODES;                     // N_NODES
    int*   flag  = tb + N_NODES;                     // 1 (padded to 4 for alignment)
    float* agg   = (float*)(flag + 4);               // MODES*BATCH*DIM
    float* cntf  = agg + MODES * BATCH * DIM;        // MODES*BATCH
    float* E_rel = cntf + MODES * BATCH;             // NUM_RELS*DIM
    float* Y_rel = E_rel + NUM_RELS * DIM;           // MODES*NUM_RELS*DIM

    k_detect<<<1, 1, 0, stream>>>(rel_vectors, flag);
    k_fill<<<256, 256, 0, stream>>>(hb, 2 * N_NODES, agg, MODES * BATCH * (DIM + 1));
    k_scatter<<<(BATCH + 255) / 256, 256, 0, stream>>>(head_ids, tail_ids, hb, tb, BATCH);
    k_rel<<<NUM_RELS, DIM, 0, stream>>>(rel_vectors, W1, b1, W2, b2, reld_W, reld_b,
                                        flag, E_rel, Y_rel);
    k_edges<<<(n_edges + 255) / 256, 256, 0, stream>>>(edge_src, edge_dst, edge_type,
                                                       hb, tb, Y_rel, agg, cntf, n_edges);
    k_final<<<BATCH, DIM, 0, stream>>>(agg, cntf, E_rel, rel_labels,
                                       conc_W, conc_b, fc_W, fc_b, flag, d_out);
}

// Round 2
// 129.526 us; speedup vs baseline: 1.1996x; 1.1996x over previous
//
#include <hip/hip_runtime.h>
#include <hip/hip_bf16.h>

// Problem constants (fixed by the reference's setup_inputs).
constexpr int N_NODES  = 100000;
constexpr int BATCH    = 256;
constexpr int NUM_RELS = 200;
constexpr int VEC      = 300;
constexpr int DIM      = 32;
constexpr int MODES    = 6;

constexpr int BM_WORDS     = (N_NODES + 31) / 32;   // 3125 words = 12.5 KB (fits in L1)
constexpr int RELS_PER_BLK = 8;                     // full 256-thread blocks in K1
constexpr int NRB          = NUM_RELS / RELS_PER_BLK; // 25 (200 % 8 == 0)
static_assert(NUM_RELS % RELS_PER_BLK == 0, "rel blocks assume exact tiling");
constexpr int ZERO_BLKS    = 64;

// ---- dtype-generic scalar load ---------------------------------------------
template <typename T> __device__ __forceinline__ float ldf(const void* p, int i);
template <> __device__ __forceinline__ float ldf<float>(const void* p, int i) {
    return ((const float*)p)[i];
}
template <> __device__ __forceinline__ float ldf<__hip_bfloat16>(const void* p, int i) {
    return __bfloat162float(((const __hip_bfloat16*)p)[i]);
}

// ---- per-block bf16-vs-fp32 detect (wave 0, one ballot) --------------------
// bf16 N(0,1) halfwords have exponent <= ~129; fp32 data read as halfwords has
// wild exponents in the low-mantissa halves with probability ~1.
__device__ __forceinline__ void detect_dtype(const void* rel_vectors, int* sflag) {
    const int tid = threadIdx.x;
    if (tid < 64) {
        unsigned short p = ((const unsigned short*)rel_vectors)[tid];
        unsigned long long mk = __ballot(((p >> 7) & 0xFF) > 140);
        if (tid == 0) *sflag = (mk == 0ull);
    }
    __syncthreads();
}

// ---- K1: fused setup -------------------------------------------------------
// block 0            : clear bitmap, scatter head/tail -> bitmap + pack
// blocks 1..NRB      : E_rel / Y_rel for 8 relations each (full wave64 use)
// blocks NRB+1..end  : zero cnt3
template <typename T>
__device__ __forceinline__ void rel_body(const void* rel_vectors, const void* W1, const void* b1,
                                         const void* W2, const void* b2,
                                         const void* reld_W, const void* reld_b,
                                         float* E_rel, float* Y_rel,
                                         float (*rv)[VEC], float (*e1)[DIM], float (*e2)[DIM],
                                         int r0) {
    const int tid = threadIdx.x;
    const int g = tid >> 5, d = tid & 31;
    const int r = r0 + g;                       // always < NUM_RELS (exact tiling)
    for (int v = d; v < VEC; v += 32) rv[g][v] = ldf<T>(rel_vectors, r * VEC + v);
    __syncthreads();
    float acc = ldf<T>(b1, d);
    for (int v = 0; v < VEC; ++v) acc += rv[g][v] * ldf<T>(W1, v * DIM + d);
    e1[g][d] = acc;
    __syncthreads();
    float a2 = ldf<T>(b2, d);
    for (int k = 0; k < DIM; ++k) a2 += e1[g][k] * ldf<T>(W2, k * DIM + d);
    e2[g][d] = a2;
    E_rel[r * DIM + d] = a2;
    __syncthreads();
    for (int m = 0; m < MODES; ++m) {
        float y = ldf<T>(reld_b, m * DIM + d);
        for (int k = 0; k < DIM; ++k) y += e2[g][k] * ldf<T>(reld_W, (m * DIM + k) * DIM + d);
        Y_rel[(m * NUM_RELS + r) * DIM + d] = y;
    }
}

__global__ void k_setup(const int* __restrict__ head_ids, const int* __restrict__ tail_ids,
                        const void* rel_vectors, const void* W1, const void* b1,
                        const void* W2, const void* b2,
                        const void* reld_W, const void* reld_b,
                        unsigned* bitmap, unsigned* pack, unsigned* cnt3,
                        float* E_rel, float* Y_rel) {
    __shared__ float rv[RELS_PER_BLK][VEC];
    __shared__ float e1[RELS_PER_BLK][DIM];
    __shared__ float e2[RELS_PER_BLK][DIM];
    __shared__ int sflag;
    const int bid = blockIdx.x, tid = threadIdx.x;
    if (bid == 0) {
        for (int i = tid; i < BM_WORDS; i += blockDim.x) bitmap[i] = 0u;
        __syncthreads();
        if (tid < BATCH) {                       // zero only the entries we will OR into
            pack[head_ids[tid]] = 0u;
            pack[tail_ids[tid]] = 0u;
        }
        __syncthreads();
        if (tid < BATCH) {
            const int h = head_ids[tid], t = tail_ids[tid];
            atomicOr(&pack[h], (unsigned)(tid + 1));
            atomicOr(&pack[t], (unsigned)(tid + 1) << 16);
            atomicOr(&bitmap[h >> 5], 1u << (h & 31));
            atomicOr(&bitmap[t >> 5], 1u << (t & 31));
        }
    } else if (bid <= NRB) {
        detect_dtype(rel_vectors, &sflag);
        const int r0 = (bid - 1) * RELS_PER_BLK;
        if (sflag)
            rel_body<__hip_bfloat16>(rel_vectors, W1, b1, W2, b2, reld_W, reld_b,
                                     E_rel, Y_rel, rv, e1, e2, r0);
        else
            rel_body<float>(rel_vectors, W1, b1, W2, b2, reld_W, reld_b,
                            E_rel, Y_rel, rv, e1, e2, r0);
    } else {
        uint4* p = (uint4*)cnt3;
        const int n4 = (MODES * BATCH * NUM_RELS) / 4;
        const int idx = (bid - 1 - NRB) * blockDim.x + tid;
        const int stride = ZERO_BLKS * blockDim.x;
        const uint4 z = {0u, 0u, 0u, 0u};
        for (int i = idx; i < n4; i += stride) p[i] = z;
    }
}

// ---- K2: edge scan — bitmap test + one u32 atomic per (mode, contribution) -
__device__ __forceinline__ void process_edge(int s, int dn, int t, unsigned bs, unsigned bd,
                                             const unsigned* __restrict__ pack,
                                             unsigned* cnt3) {
    const unsigned ps = bs ? pack[s] : 0u;       // pack valid only where bitmap set
    const unsigned pd = bd ? pack[dn] : 0u;
    const int hbs = (int)(ps & 0xFFFFu) - 1, tbs = (int)(ps >> 16) - 1;
    const int hbd = (int)(pd & 0xFFFFu) - 1, tbd = (int)(pd >> 16) - 1;
    const bool m5 = (hbs >= 0) && (hbs == tbd);
    const bool m6 = (hbd >= 0) && (hbd == tbs);
    if (hbd >= 0)         atomicAdd(&cnt3[((m6 ? 5 : 0) * BATCH + hbd) * NUM_RELS + t], 1u);
    if (hbs >= 0)         atomicAdd(&cnt3[((m5 ? 4 : 1) * BATCH + hbs) * NUM_RELS + t], 1u);
    if (tbd >= 0 && !m5)  atomicAdd(&cnt3[(2 * BATCH + tbd) * NUM_RELS + t], 1u);
    if (tbs >= 0 && !m6)  atomicAdd(&cnt3[(3 * BATCH + tbs) * NUM_RELS + t], 1u);
}

__global__ void k_edges(const int* __restrict__ src, const int* __restrict__ dst,
                        const int* __restrict__ typ,
                        const unsigned* __restrict__ bitmap, const unsigned* __restrict__ pack,
                        unsigned* cnt3, int n_edges) {
    const int n4 = n_edges >> 2;
    const int gstride = gridDim.x * blockDim.x;
    const int gtid = blockIdx.x * blockDim.x + threadIdx.x;
    const int4* src4 = (const int4*)src;
    const int4* dst4 = (const int4*)dst;
    for (int i = gtid; i < n4; i += gstride) {
        const int4 s4 = src4[i];
        const int4 d4 = dst4[i];
        #pragma unroll
        for (int j = 0; j < 4; ++j) {
            const int s  = (&s4.x)[j];
            const int dn = (&d4.x)[j];
            const unsigned bs = (bitmap[s  >> 5] >> (s  & 31)) & 1u;
            const unsigned bd = (bitmap[dn >> 5] >> (dn & 31)) & 1u;
            if (!(bs | bd)) continue;            // ~99% of edges
            process_edge(s, dn, typ[i * 4 + j], bs, bd, pack, cnt3);
        }
    }
    const int rem = n_edges & 3;
    if (gtid < rem) {
        const int e = n4 * 4 + gtid;
        const int s = src[e], dn = dst[e];
        const unsigned bs = (bitmap[s  >> 5] >> (s  & 31)) & 1u;
        const unsigned bd = (bitmap[dn >> 5] >> (dn & 31)) & 1u;
        if (bs | bd) process_edge(s, dn, typ[e], bs, bd, pack, cnt3);
    }
}

// ---- K3: fused epilogue ----------------------------------------------------
// block b, 192 threads: (m = tid/32, d = tid%32). agg[m,b,d] = sum_t c*Y_rel,
// then mean-of-means -> concat MLP -> relu -> L2 norm -> fc.
template <typename T>
__device__ __forceinline__ void final_body(const unsigned* __restrict__ cnt3,
                                           const float* __restrict__ E_rel,
                                           const float* __restrict__ Y_rel,
                                           const int* __restrict__ rel_labels,
                                           const void* conc_W, const void* conc_b,
                                           const void* fc_W, const void* fc_b,
                                           void* out, float* sm, float* cat) {
    const int b = blockIdx.x, tid = threadIdx.x;
    const int m = tid >> 5, d = tid & 31;
    float acc = 0.f, tot = 0.f;
    const unsigned* row = cnt3 + (m * BATCH + b) * NUM_RELS;
    const float* Ym = Y_rel + m * NUM_RELS * DIM;
    #pragma unroll 4
    for (int t = 0; t < NUM_RELS; ++t) {
        const unsigned c = row[t];
        if (c) {
            const float cf = (float)c;
            acc += cf * Ym[t * DIM + d];
            tot += cf;
        }
    }
    sm[m * DIM + d] = acc / (tot + 1e-30f);
    __syncthreads();
    if (tid < DIM) {
        float rn = 0.f;
        for (int mm = 0; mm < MODES; ++mm) rn += sm[mm * DIM + tid];
        cat[tid] = rn / (float)MODES;
        cat[DIM + tid] = E_rel[rel_labels[b] * DIM + tid];
    }
    __syncthreads();
    if (tid < DIM) {
        float h = ldf<T>(conc_b, tid);
        for (int k = 0; k < 2 * DIM; ++k) h += cat[k] * ldf<T>(conc_W, k * DIM + tid);
        h = fmaxf(h, 0.f);
        float n2 = h * h;
        #pragma unroll
        for (int off = 16; off >= 1; off >>= 1) n2 += __shfl_xor(n2, off);
        const float g = h / fmaxf(sqrtf(n2), 1e-12f);
        float pr = g * ldf<T>(fc_W, tid);
        #pragma unroll
        for (int off = 16; off >= 1; off >>= 1) pr += __shfl_xor(pr, off);
        if (tid == 0) {
            const float o = pr + ldf<T>(fc_b, 0);
            if constexpr (sizeof(T) == 2) ((__hip_bfloat16*)out)[b] = __float2bfloat16(o);
            else                          ((float*)out)[b] = o;
        }
    }
}

__global__ void k_final(const unsigned* __restrict__ cnt3, const float* __restrict__ E_rel,
                        const float* __restrict__ Y_rel, const int* __restrict__ rel_labels,
                        const void* rel_vectors,
                        const void* conc_W, const void* conc_b,
                        const void* fc_W, const void* fc_b, void* out) {
    __shared__ float sm[MODES * DIM];
    __shared__ float cat[2 * DIM];
    __shared__ int sflag;
    detect_dtype(rel_vectors, &sflag);
    if (sflag)
        final_body<__hip_bfloat16>(cnt3, E_rel, Y_rel, rel_labels, conc_W, conc_b, fc_W, fc_b, out, sm, cat);
    else
        final_body<float>(cnt3, E_rel, Y_rel, rel_labels, conc_W, conc_b, fc_W, fc_b, out, sm, cat);
}

extern "C" void kernel_launch(void* const* d_in, const int* in_sizes, int n_in,
                              void* d_out, int out_size, void* d_ws, size_t ws_size,
                              hipStream_t stream) {
    const int* edge_src   = (const int*)d_in[0];
    const int* edge_dst   = (const int*)d_in[1];
    const int* edge_type  = (const int*)d_in[2];
    const int* head_ids   = (const int*)d_in[3];
    const int* tail_ids   = (const int*)d_in[4];
    const int* rel_labels = (const int*)d_in[5];
    const void* rel_vectors = d_in[6];
    const void* W1     = d_in[7];
    const void* b1     = d_in[8];
    const void* W2     = d_in[9];
    const void* b2     = d_in[10];
    const void* reld_W = d_in[11];
    const void* reld_b = d_in[12];
    const void* conc_W = d_in[13];
    const void* conc_b = d_in[14];
    const void* fc_W   = d_in[15];
    const void* fc_b   = d_in[16];

    const int n_edges = in_sizes[0];

    // workspace layout (~1.8 MB)
    unsigned* cnt3   = (unsigned*)d_ws;                  // MODES*BATCH*NUM_RELS (zeroed in K1)
    unsigned* bitmap = cnt3 + MODES * BATCH * NUM_RELS;  // BM_WORDS (zeroed in K1 block 0)
    unsigned* pack   = bitmap + BM_WORDS;                // N_NODES (read only where bitmap set)
    float*    E_rel  = (float*)(pack + N_NODES);         // NUM_RELS*DIM
    float*    Y_rel  = E_rel + NUM_RELS * DIM;           // MODES*NUM_RELS*DIM

    k_setup<<<1 + NRB + ZERO_BLKS, 256, 0, stream>>>(head_ids, tail_ids,
                                                     rel_vectors, W1, b1, W2, b2, reld_W, reld_b,
                                                     bitmap, pack, cnt3, E_rel, Y_rel);
    k_edges<<<512, 256, 0, stream>>>(edge_src, edge_dst, edge_type,
                                     bitmap, pack, cnt3, n_edges);
    k_final<<<BATCH, 192, 0, stream>>>(cnt3, E_rel, Y_rel, rel_labels, rel_vectors,
                                       conc_W, conc_b, fc_W, fc_b, d_out);
}